// Round 1
// baseline (119.637 us; speedup 1.0000x reference)
//
#include <hip/hip_runtime.h>
#include <hip/hip_bf16.h>
#include <cstdint>
#include <cstddef>

// Problem constants (reference: B=8, S=4096, N_STATE=1024, N_HEAD=16)
#define B_SZ    8
#define S_LEN   4096
#define NHEAD   16
#define HDIM    64
#define NROT    32
#define NFREQ   32                      // HDIM/2
#define NROWS   (B_SZ * S_LEN * NHEAD)  // 524288 rows of 64 floats
#define NGROUPS (NROWS / 16)            // 32768 groups of 16 rows (one (b,s) each)

typedef __attribute__((address_space(1))) unsigned int gu32;
typedef __attribute__((address_space(3))) unsigned int lu32;

// ---------------------------------------------------------------------------
// Setup: blocks 0..511 fill the RoPE sin/cos tables (4096 x 32 each);
// block 512 composes M = G0*G1*...*G31 * R and stores it transposed:
// Mt[c*64 + k] = M[k][c]  (so lane c of the main kernel loads row c of Mt).
// ---------------------------------------------------------------------------
__global__ void setup_kernel(const float* __restrict__ thetas,
                             const float* __restrict__ theta_scale,
                             const float* __restrict__ r_matrix,
                             const int*   __restrict__ r_pairs,
                             const float* __restrict__ inv_freq,
                             float* __restrict__ Mt,
                             float* __restrict__ cosT,
                             float* __restrict__ sinT) {
  if (blockIdx.x < 512) {
    int idx = blockIdx.x * 256 + threadIdx.x;   // 0 .. 131071 = s*32 + f
    int s = idx >> 5;
    int f = idx & 31;
    float ang = (float)s * inv_freq[f];
    cosT[idx] = cosf(ang);
    sinT[idx] = sinf(ang);
    return;
  }
  // block 512: build the combined rotation matrix.
  __shared__ float C[64 * 65];                  // pad 65 to avoid bank conflicts
  int tid = threadIdx.x;
  if (tid < 64) {
    // row `tid` of C = identity
    for (int c = 0; c < 64; ++c) C[tid * 65 + c] = (tid == c) ? 1.0f : 0.0f;
    float sc = theta_scale[0];
    // apply the scan's column rotations to C (each thread owns one row -> no races)
    for (int q = 0; q < NROT; ++q) {
      float th = thetas[q] * sc;
      float cs = cosf(th), sn = sinf(th);
      int i = r_pairs[2 * q], j = r_pairs[2 * q + 1];
      float xi = C[tid * 65 + i];
      float xj = C[tid * 65 + j];
      C[tid * 65 + i] =  xi * cs + xj * sn;
      C[tid * 65 + j] = -xi * sn + xj * cs;
    }
  }
  __syncthreads();
  // Mt[c][t] = sum_k C[t][k] * R[k][c]
  for (int o = tid; o < 64 * 64; o += 256) {
    int t = o >> 6, c = o & 63;
    float a = 0.0f;
    for (int k = 0; k < 64; ++k) a = fmaf(C[t * 65 + k], r_matrix[k * 64 + c], a);
    Mt[c * 64 + t] = a;
  }
}

// ---------------------------------------------------------------------------
// Main: lane c holds column c of M in registers. Each wave independently
// stages 16 rows (4KB, one (b,s) group) to its private LDS buffer via
// global_load_lds, then per row: 16 broadcast ds_read_b128 + 64 FMAs,
// DPP shfl_xor(1) for the RoPE even/odd pairing, 1 dword store per lane.
// ---------------------------------------------------------------------------
__global__ __launch_bounds__(256, 4)
void rotary_main(const float* __restrict__ x,
                 const float* __restrict__ Mt,
                 const float* __restrict__ cosT,
                 const float* __restrict__ sinT,
                 float* __restrict__ out) {
  __shared__ float sx[4 * 2 * 1024];            // 4 waves x 2 buffers x 1024 floats = 32KB
  const int tid  = threadIdx.x;
  const int lane = tid & 63;
  const int wid  = tid >> 6;
  const int d    = lane >> 1;                   // RoPE frequency index for this lane pair

  // lane c's column of M (one-time, 16 float4 = 64 VGPRs)
  float4 m4[16];
  #pragma unroll
  for (int kb = 0; kb < 16; ++kb)
    m4[kb] = *reinterpret_cast<const float4*>(Mt + lane * 64 + kb * 4);

  const int gw0     = blockIdx.x * 4 + wid;
  const int gstride = gridDim.x * 4;
  int buf = 0;

  for (int g = gw0; g < NGROUPS; g += gstride) {
    const int s = g & (S_LEN - 1);              // g = b*S + s
    float cv = cosT[s * NFREQ + d];
    float sv = sinT[s * NFREQ + d];

    float* sxw = sx + wid * 2048 + buf * 1024;  // this wave's buffer
    const float* xg = x + (size_t)g * 1024;

    // stage 16 rows = 4KB: 4 calls x (64 lanes x 16B), perfectly coalesced
    #pragma unroll
    for (int i = 0; i < 4; ++i) {
      __builtin_amdgcn_global_load_lds(
          (gu32*)(const void*)(xg + i * 256 + lane * 4),
          (lu32*)(void*)(sxw + i * 256),
          16, 0, 0);
    }
    __builtin_amdgcn_sched_barrier(0);
    asm volatile("s_waitcnt vmcnt(0)" ::: "memory");
    __builtin_amdgcn_sched_barrier(0);

    const int col = (lane & 1) ? (32 + d) : d;
    float* op = out + (size_t)g * 1024 + col;

    for (int r4 = 0; r4 < 4; ++r4) {
      #pragma unroll
      for (int r2 = 0; r2 < 4; ++r2) {
        const int rr = r4 * 4 + r2;
        const float* xr = sxw + rr * 64;
        float ax = 0.f, ay = 0.f, az = 0.f, aw = 0.f;
        #pragma unroll
        for (int kb = 0; kb < 16; ++kb) {
          float4 xv = *reinterpret_cast<const float4*>(xr + kb * 4); // broadcast read
          float4 mv = m4[kb];
          ax = fmaf(xv.x, mv.x, ax);
          ay = fmaf(xv.y, mv.y, ay);
          az = fmaf(xv.z, mv.z, az);
          aw = fmaf(xv.w, mv.w, aw);
        }
        float y = (ax + ay) + (az + aw);        // y[row][lane]
        float p = __shfl_xor(y, 1, 64);         // partner column (DPP, no LDS)
        // even lane (c=2d): out[d]    = y[2d]*cos - y[2d+1]*sin
        // odd  lane (c=2d+1): out[32+d] = y[2d]*sin + y[2d+1]*cos
        float o = (lane & 1) ? fmaf(p, sv, y * cv) : fmaf(y, cv, -(p * sv));
        op[rr * 64] = o;
      }
    }
    buf ^= 1;
  }
}

extern "C" void kernel_launch(void* const* d_in, const int* in_sizes, int n_in,
                              void* d_out, int out_size, void* d_ws, size_t ws_size,
                              hipStream_t stream) {
  const float* x           = (const float*)d_in[0];
  const float* thetas      = (const float*)d_in[1];
  const float* theta_scale = (const float*)d_in[2];
  const float* r_matrix    = (const float*)d_in[3];
  const float* inv_freq    = (const float*)d_in[4];
  const int*   r_pairs     = (const int*)d_in[5];

  float* Mt   = (float*)d_ws;                   // 4096 floats (16KB)
  float* cosT = Mt + 4096;                      // 131072 floats (512KB)
  float* sinT = cosT + S_LEN * NFREQ;           // 131072 floats (512KB)
  float* outp = (float*)d_out;

  setup_kernel<<<513, 256, 0, stream>>>(thetas, theta_scale, r_matrix, r_pairs,
                                        inv_freq, Mt, cosT, sinT);
  rotary_main<<<2048, 256, 0, stream>>>(x, Mt, cosT, sinT, outp);
}